// Round 3
// baseline (399.685 us; speedup 1.0000x reference)
//
#include <hip/hip_runtime.h>

// ---------------------------------------------------------------------------
// MultiAttention: x[T=1024,N=8,D=1024] -> QKV proj -> 16-head causal attention
// with key padding -> out proj. bf16 MFMA compute, f32 accumulation.
// Round 3: R1 fast pipeline + fixed (encoding-detecting) key_padding_mask read.
// ---------------------------------------------------------------------------

#define T_SEQ 1024
#define NB 8
#define DMODEL 1024
#define NHEADS 16
#define DK 64

typedef __attribute__((ext_vector_type(8))) short bf16x8;
typedef __attribute__((ext_vector_type(4))) float f32x4;

#define MFMA16(a, b, c) __builtin_amdgcn_mfma_f32_16x16x32_bf16((a), (b), (c), 0, 0, 0)

__device__ __forceinline__ unsigned short f2bf(float f) {
  unsigned int u = __float_as_uint(f);
  unsigned int r = (u + 0x7FFFu + ((u >> 16) & 1u)) >> 16;  // RNE
  return (unsigned short)r;
}

__device__ __forceinline__ void gload16(const void* g, void* l) {
  __builtin_amdgcn_global_load_lds((const __attribute__((address_space(1))) void*)g,
                                   (__attribute__((address_space(3))) void*)l, 16, 0, 0);
}

// ---------------- f32 -> bf16 conversion (vectorized) ----------------------
__global__ __launch_bounds__(256) void cvt_f32_bf16(const float* __restrict__ in,
                                                    unsigned short* __restrict__ out,
                                                    int n4) {
  int i = blockIdx.x * blockDim.x + threadIdx.x;
  if (i >= n4) return;
  float4 v = reinterpret_cast<const float4*>(in)[i];
  uint2 o;
  o.x = (unsigned)f2bf(v.x) | ((unsigned)f2bf(v.y) << 16);
  o.y = (unsigned)f2bf(v.z) | ((unsigned)f2bf(v.w) << 16);
  reinterpret_cast<uint2*>(out)[i] = o;
}

// ---------------- per-batch valid length from key_padding_mask -------------
// The harness may push the bool mask as int32 (documented: integer -> int*),
// uint8, or even f32. Detect element width from the first 8192 bytes (safe to
// read under every encoding): if all int32 words are in {0, 1, 0x3F800000},
// elements are 4-byte; else 1-byte. For this input the detection is
// unambiguous (packed uint8 bools produce words like 0x01010101).
__global__ void len_kernel(const void* __restrict__ kpm_raw, int* __restrict__ lens) {
  const int* ki = (const int*)kpm_raw;
  const unsigned char* kb = (const unsigned char*)kpm_raw;
  const int lane = threadIdx.x;  // 1 block, 64 threads
  int bad = 0;
  for (int i = lane; i < 2048; i += 64) {
    unsigned v = (unsigned)ki[i];
    bad |= (v != 0u && v != 1u && v != 0x3F800000u) ? 1 : 0;
  }
  bad = __any(bad);  // 1 -> byte elements, 0 -> 4-byte elements
  for (int n = 0; n < NB; ++n) {
    int cnt = 0;
    if (bad) {
      for (int s = lane; s < T_SEQ; s += 64) cnt += (kb[n * T_SEQ + s] == 0) ? 1 : 0;
    } else {
      for (int s = lane; s < T_SEQ; s += 64) cnt += (ki[n * T_SEQ + s] == 0) ? 1 : 0;
    }
    for (int m = 1; m < 64; m <<= 1) cnt += __shfl_xor(cnt, m);
    if (lane == 0) lens[n] = cnt;
  }
}

// ---------------- 128x128 bf16 GEMM, C = A * B^T + bias --------------------
// A: [M,K] bf16 row-major. B: [N,K] bf16 row-major (i.e. B^T input form).
// EPI==0: scatter epilogue to q/k/vt buffers (QKV projection).
// EPI==1: f32 output C[row*N + col] (output projection).
template <int EPI>
__global__ __launch_bounds__(256) void gemm_bt_kernel(
    const unsigned short* __restrict__ A, const unsigned short* __restrict__ B,
    const float* __restrict__ bias, float* __restrict__ Cf,
    unsigned short* __restrict__ qb, unsigned short* __restrict__ kb,
    unsigned short* __restrict__ vtb, int M, int N, int K) {
  __shared__ unsigned short lds_a[128 * 32];
  __shared__ unsigned short lds_b[128 * 32];
  const int tid = threadIdx.x;
  const int brow = blockIdx.x * 128;
  const int bcol = blockIdx.y * 128;
  const int w = tid >> 6, lane = tid & 63;
  const int l15 = lane & 15, lg = lane >> 4;
  const int wr = (w >> 1) * 64, wc = (w & 1) * 64;  // 2x2 wave grid, 64x64 each

  f32x4 acc[4][4] = {};

  for (int k0 = 0; k0 < K; k0 += 32) {
#pragma unroll
    for (int i = 0; i < 2; ++i) {
      int seg = i * 256 + tid;           // 512 segments of 16B per tile
      int row = seg >> 2;
      int qq = (seg & 3) * 8;
      gload16(A + (size_t)(brow + row) * K + k0 + qq, lds_a + seg * 8);
      gload16(B + (size_t)(bcol + row) * K + k0 + qq, lds_b + seg * 8);
    }
    __syncthreads();  // drains vmcnt -> staged data visible
    bf16x8 af[4], bfr[4];
#pragma unroll
    for (int mi = 0; mi < 4; ++mi)
      af[mi] = *reinterpret_cast<const bf16x8*>(lds_a + (wr + mi * 16 + l15) * 32 + lg * 8);
#pragma unroll
    for (int ni = 0; ni < 4; ++ni)
      bfr[ni] = *reinterpret_cast<const bf16x8*>(lds_b + (wc + ni * 16 + l15) * 32 + lg * 8);
#pragma unroll
    for (int mi = 0; mi < 4; ++mi)
#pragma unroll
      for (int ni = 0; ni < 4; ++ni)
        acc[mi][ni] = MFMA16(af[mi], bfr[ni], acc[mi][ni]);
    __syncthreads();  // all reads done before next stage overwrites
  }

#pragma unroll
  for (int mi = 0; mi < 4; ++mi) {
#pragma unroll
    for (int ni = 0; ni < 4; ++ni) {
      const int col = bcol + wc + ni * 16 + l15;
      const float bv = bias[col];
#pragma unroll
      for (int r = 0; r < 4; ++r) {
        const int row = brow + wr + mi * 16 + lg * 4 + r;  // C/D layout rows
        const float v = acc[mi][ni][r] + bv;
        if (EPI == 1) {
          Cf[(size_t)row * N + col] = v;
        } else {
          const int t = row >> 3, n = row & 7;  // row = t*NB + n
          const unsigned short hv = f2bf(v);
          if (col < DMODEL) {  // Q -> [n,h,t,dk]
            const int h = col >> 6, dk = col & 63;
            qb[(size_t)(n * NHEADS + h) * (T_SEQ * DK) + t * DK + dk] = hv;
          } else if (col < 2 * DMODEL) {  // K -> [n,h,t,dk]
            const int c2 = col - DMODEL;
            const int h = c2 >> 6, dk = c2 & 63;
            kb[(size_t)(n * NHEADS + h) * (T_SEQ * DK) + t * DK + dk] = hv;
          } else {  // V -> transposed [n,h,dk,t]
            const int c2 = col - 2 * DMODEL;
            const int h = c2 >> 6, dk = c2 & 63;
            vtb[(size_t)(n * NHEADS + h) * (T_SEQ * DK) + (size_t)dk * T_SEQ + t] = hv;
          }
        }
      }
    }
  }
}

// ---------------- fused causal attention, online softmax ------------------
// grid: (N*H)*16 blocks; block = 4 waves; wave w owns 16 q-rows.
// Q,K from [n,h,t,dk]; V from [n,h,dk,t] (transposed); P via padded LDS.
#define PLD 72  // 72*2=144B row stride: breaks the stride-128B bank pattern

__global__ __launch_bounds__(256) void attn_kernel(
    const unsigned short* __restrict__ qb, const unsigned short* __restrict__ kb,
    const unsigned short* __restrict__ vtb, const int* __restrict__ lens,
    unsigned short* __restrict__ attn_out) {
  __shared__ unsigned short p_lds[4 * 16 * PLD];
  const int bid = blockIdx.x;
  const int nh = bid >> 4;         // (n*H + h)
  const int q0 = (bid & 15) * 64;  // q-tile start
  const int n = nh >> 4;
  const int h = nh & 15;
  const int w = threadIdx.x >> 6, lane = threadIdx.x & 63;
  const int l15 = lane & 15, lg = lane >> 4;
  const int len_n = lens[n];

  // Q fragments (A-operand layout: row = l15, k = kk*32 + lg*8)
  const unsigned short* qp = qb + (size_t)nh * (T_SEQ * DK) + (size_t)(q0 + w * 16 + l15) * DK;
  const bf16x8 qa0 = *reinterpret_cast<const bf16x8*>(qp + lg * 8);
  const bf16x8 qa1 = *reinterpret_cast<const bf16x8*>(qp + 32 + lg * 8);

  const unsigned short* kp_base = kb + (size_t)nh * (T_SEQ * DK);
  const unsigned short* vp_base = vtb + (size_t)nh * (T_SEQ * DK);
  unsigned short* pw = p_lds + w * 16 * PLD;

  f32x4 o_acc[4] = {};
  float m_r[4], l_r[4];
#pragma unroll
  for (int r = 0; r < 4; ++r) { m_r[r] = -1e30f; l_r[r] = 0.f; }

  const int t_base = q0 + w * 16 + lg * 4;  // C/D layout row base
  int ntiles = q0 / 64 + 1;                 // causal bound (same for all 4 waves)
  const int ltiles = (len_n + 63) >> 6;     // padding bound
  if (ltiles < ntiles) ntiles = ltiles;

  for (int tile = 0; tile < ntiles; ++tile) {
    const int s0 = tile * 64;
    f32x4 s_acc[4] = {};
#pragma unroll
    for (int ct = 0; ct < 4; ++ct) {  // S = Q K^T  (B-operand = K rows)
      const unsigned short* kp = kp_base + (size_t)(s0 + ct * 16 + l15) * DK + lg * 8;
      const bf16x8 kb0 = *reinterpret_cast<const bf16x8*>(kp);
      const bf16x8 kb1 = *reinterpret_cast<const bf16x8*>(kp + 32);
      s_acc[ct] = MFMA16(qa0, kb0, s_acc[ct]);
      s_acc[ct] = MFMA16(qa1, kb1, s_acc[ct]);
    }
    // scale + causal/padding mask
    float sv[4][4];
#pragma unroll
    for (int ct = 0; ct < 4; ++ct) {
      const int s = s0 + ct * 16 + l15;
#pragma unroll
      for (int r = 0; r < 4; ++r) {
        const int t = t_base + r;
        const float v = s_acc[ct][r] * 0.125f;  // 1/sqrt(64)
        sv[ct][r] = (s > t || s >= len_n) ? -1e30f : v;
      }
    }
    // online softmax per row r (row-reduce across the 16-lane group)
#pragma unroll
    for (int r = 0; r < 4; ++r) {
      float mx = fmaxf(fmaxf(sv[0][r], sv[1][r]), fmaxf(sv[2][r], sv[3][r]));
      mx = fmaxf(mx, __shfl_xor(mx, 1));
      mx = fmaxf(mx, __shfl_xor(mx, 2));
      mx = fmaxf(mx, __shfl_xor(mx, 4));
      mx = fmaxf(mx, __shfl_xor(mx, 8));
      const float mnew = fmaxf(m_r[r], mx);
      const float sc = __expf(m_r[r] - mnew);
      m_r[r] = mnew;
      float rs = 0.f;
#pragma unroll
      for (int ct = 0; ct < 4; ++ct) {
        const float p = __expf(sv[ct][r] - mnew);
        sv[ct][r] = p;
        rs += p;
      }
      rs += __shfl_xor(rs, 1);
      rs += __shfl_xor(rs, 2);
      rs += __shfl_xor(rs, 4);
      rs += __shfl_xor(rs, 8);
      l_r[r] = l_r[r] * sc + rs;
#pragma unroll
      for (int ct = 0; ct < 4; ++ct) o_acc[ct][r] *= sc;
      // write P (bf16) into per-wave LDS slab, [row][s] layout
#pragma unroll
      for (int ct = 0; ct < 4; ++ct)
        pw[(lg * 4 + r) * PLD + ct * 16 + l15] = f2bf(sv[ct][r]);
    }
    __syncthreads();  // P writes visible before A-fragment reads
    // PV: A-operand from LDS P, B-operand = contiguous rows of V^T
    const bf16x8 pa0 = *reinterpret_cast<const bf16x8*>(pw + l15 * PLD + lg * 8);
    const bf16x8 pa1 = *reinterpret_cast<const bf16x8*>(pw + l15 * PLD + 32 + lg * 8);
#pragma unroll
    for (int ct = 0; ct < 4; ++ct) {
      const unsigned short* vp = vp_base + (size_t)(ct * 16 + l15) * T_SEQ + s0 + lg * 8;
      const bf16x8 vb0 = *reinterpret_cast<const bf16x8*>(vp);
      const bf16x8 vb1 = *reinterpret_cast<const bf16x8*>(vp + 32);
      o_acc[ct] = MFMA16(pa0, vb0, o_acc[ct]);
      o_acc[ct] = MFMA16(pa1, vb1, o_acc[ct]);
    }
  }

  // epilogue: normalize by l and store attn output bf16 [t, n, d]
  float inv_l[4];
#pragma unroll
  for (int r = 0; r < 4; ++r) inv_l[r] = 1.0f / l_r[r];
#pragma unroll
  for (int ct = 0; ct < 4; ++ct) {
    const int d = h * DK + ct * 16 + l15;
#pragma unroll
    for (int r = 0; r < 4; ++r) {
      const int t = t_base + r;
      attn_out[((size_t)t * NB + n) * DMODEL + d] = f2bf(o_acc[ct][r] * inv_l[r]);
    }
  }
}

// ---------------------------------------------------------------------------
extern "C" void kernel_launch(void* const* d_in, const int* in_sizes, int n_in,
                              void* d_out, int out_size, void* d_ws, size_t ws_size,
                              hipStream_t stream) {
  const float* x = (const float*)d_in[0];
  const float* w_in = (const float*)d_in[1];
  const float* b_in = (const float*)d_in[2];
  const float* w_o = (const float*)d_in[3];
  const float* b_o = (const float*)d_in[4];
  // d_in[5] attn_mask: causal triu(k=1) -- computed analytically in-kernel
  const void* kpm = (const void*)d_in[6];
  float* out = (float*)d_out;

  char* ws = (char*)d_ws;
  // workspace layout (bytes)
  unsigned short* x_bf = (unsigned short*)(ws + 0);           // 16.78 MB
  unsigned short* win_bf = (unsigned short*)(ws + 16777216);  // 6.29 MB
  unsigned short* wo_bf = (unsigned short*)(ws + 23068672);   // 2.10 MB
  unsigned short* qb = (unsigned short*)(ws + 25165824);      // 16.78 MB
  unsigned short* kb = (unsigned short*)(ws + 41943040);      // 16.78 MB
  unsigned short* vtb = (unsigned short*)(ws + 58720256);     // 16.78 MB
  unsigned short* attn_bf = (unsigned short*)(ws + 75497472); // 16.78 MB
  int* lens = (int*)(ws + 92274688);                          // 32 B

  // conversions
  cvt_f32_bf16<<<(T_SEQ * NB * DMODEL / 4 + 255) / 256, 256, 0, stream>>>(x, x_bf,
                                                                          T_SEQ * NB * DMODEL / 4);
  cvt_f32_bf16<<<(3 * DMODEL * DMODEL / 4 + 255) / 256, 256, 0, stream>>>(
      w_in, win_bf, 3 * DMODEL * DMODEL / 4);
  cvt_f32_bf16<<<(DMODEL * DMODEL / 4 + 255) / 256, 256, 0, stream>>>(w_o, wo_bf,
                                                                      DMODEL * DMODEL / 4);
  len_kernel<<<1, 64, 0, stream>>>(kpm, lens);

  // QKV projection: [8192,1024] x [3072,1024]^T, scatter epilogue
  gemm_bt_kernel<0><<<dim3(64, 24), 256, 0, stream>>>(x_bf, win_bf, b_in, nullptr, qb, kb, vtb,
                                                      T_SEQ * NB, 3 * DMODEL, DMODEL);
  // fused attention
  attn_kernel<<<NB * NHEADS * (T_SEQ / 64), 256, 0, stream>>>(qb, kb, vtb, lens, attn_bf);
  // output projection: [8192,1024] x [1024,1024]^T -> f32 out
  gemm_bt_kernel<1><<<dim3(64, 8), 256, 0, stream>>>(attn_bf, wo_bf, b_o, out, nullptr, nullptr,
                                                     nullptr, T_SEQ * NB, DMODEL, DMODEL);
}

// Round 4
// 346.496 us; speedup vs baseline: 1.1535x; 1.1535x over previous
//
#include <hip/hip_runtime.h>

// ---------------------------------------------------------------------------
// MultiAttention: x[T=1024,N=8,D=1024] -> QKV proj -> 16-head causal attention
// with key padding -> out proj. bf16 MFMA compute, f32 accumulation.
// Round 4: balanced attention (paired q-tiles: every block = 17 K-tiles),
// no per-tile __syncthreads (per-wave-private P slab).
// ---------------------------------------------------------------------------

#define T_SEQ 1024
#define NB 8
#define DMODEL 1024
#define NHEADS 16
#define DK 64

typedef __attribute__((ext_vector_type(8))) short bf16x8;
typedef __attribute__((ext_vector_type(4))) float f32x4;

#define MFMA16(a, b, c) __builtin_amdgcn_mfma_f32_16x16x32_bf16((a), (b), (c), 0, 0, 0)

__device__ __forceinline__ unsigned short f2bf(float f) {
  unsigned int u = __float_as_uint(f);
  unsigned int r = (u + 0x7FFFu + ((u >> 16) & 1u)) >> 16;  // RNE
  return (unsigned short)r;
}

__device__ __forceinline__ void gload16(const void* g, void* l) {
  __builtin_amdgcn_global_load_lds((const __attribute__((address_space(1))) void*)g,
                                   (__attribute__((address_space(3))) void*)l, 16, 0, 0);
}

// ---------------- f32 -> bf16 conversion (vectorized) ----------------------
__global__ __launch_bounds__(256) void cvt_f32_bf16(const float* __restrict__ in,
                                                    unsigned short* __restrict__ out,
                                                    int n4) {
  int i = blockIdx.x * blockDim.x + threadIdx.x;
  if (i >= n4) return;
  float4 v = reinterpret_cast<const float4*>(in)[i];
  uint2 o;
  o.x = (unsigned)f2bf(v.x) | ((unsigned)f2bf(v.y) << 16);
  o.y = (unsigned)f2bf(v.z) | ((unsigned)f2bf(v.w) << 16);
  reinterpret_cast<uint2*>(out)[i] = o;
}

// ---------------- per-batch valid length from key_padding_mask -------------
// Detect element width (int32 vs byte bool) from the first 8192 bytes.
__global__ void len_kernel(const void* __restrict__ kpm_raw, int* __restrict__ lens) {
  const int* ki = (const int*)kpm_raw;
  const unsigned char* kb = (const unsigned char*)kpm_raw;
  const int lane = threadIdx.x;  // 1 block, 64 threads
  int bad = 0;
  for (int i = lane; i < 2048; i += 64) {
    unsigned v = (unsigned)ki[i];
    bad |= (v != 0u && v != 1u && v != 0x3F800000u) ? 1 : 0;
  }
  bad = __any(bad);  // 1 -> byte elements, 0 -> 4-byte elements
  for (int n = 0; n < NB; ++n) {
    int cnt = 0;
    if (bad) {
      for (int s = lane; s < T_SEQ; s += 64) cnt += (kb[n * T_SEQ + s] == 0) ? 1 : 0;
    } else {
      for (int s = lane; s < T_SEQ; s += 64) cnt += (ki[n * T_SEQ + s] == 0) ? 1 : 0;
    }
    for (int m = 1; m < 64; m <<= 1) cnt += __shfl_xor(cnt, m);
    if (lane == 0) lens[n] = cnt;
  }
}

// ---------------- 128x128 bf16 GEMM, C = A * B^T + bias --------------------
template <int EPI>
__global__ __launch_bounds__(256) void gemm_bt_kernel(
    const unsigned short* __restrict__ A, const unsigned short* __restrict__ B,
    const float* __restrict__ bias, float* __restrict__ Cf,
    unsigned short* __restrict__ qb, unsigned short* __restrict__ kb,
    unsigned short* __restrict__ vtb, int M, int N, int K) {
  __shared__ unsigned short lds_a[128 * 32];
  __shared__ unsigned short lds_b[128 * 32];
  const int tid = threadIdx.x;
  const int brow = blockIdx.x * 128;
  const int bcol = blockIdx.y * 128;
  const int w = tid >> 6, lane = tid & 63;
  const int l15 = lane & 15, lg = lane >> 4;
  const int wr = (w >> 1) * 64, wc = (w & 1) * 64;  // 2x2 wave grid, 64x64 each

  f32x4 acc[4][4] = {};

  for (int k0 = 0; k0 < K; k0 += 32) {
#pragma unroll
    for (int i = 0; i < 2; ++i) {
      int seg = i * 256 + tid;           // 512 segments of 16B per tile
      int row = seg >> 2;
      int qq = (seg & 3) * 8;
      gload16(A + (size_t)(brow + row) * K + k0 + qq, lds_a + seg * 8);
      gload16(B + (size_t)(bcol + row) * K + k0 + qq, lds_b + seg * 8);
    }
    __syncthreads();  // drains vmcnt -> staged data visible
    bf16x8 af[4], bfr[4];
#pragma unroll
    for (int mi = 0; mi < 4; ++mi)
      af[mi] = *reinterpret_cast<const bf16x8*>(lds_a + (wr + mi * 16 + l15) * 32 + lg * 8);
#pragma unroll
    for (int ni = 0; ni < 4; ++ni)
      bfr[ni] = *reinterpret_cast<const bf16x8*>(lds_b + (wc + ni * 16 + l15) * 32 + lg * 8);
#pragma unroll
    for (int mi = 0; mi < 4; ++mi)
#pragma unroll
      for (int ni = 0; ni < 4; ++ni)
        acc[mi][ni] = MFMA16(af[mi], bfr[ni], acc[mi][ni]);
    __syncthreads();  // all reads done before next stage overwrites
  }

#pragma unroll
  for (int mi = 0; mi < 4; ++mi) {
#pragma unroll
    for (int ni = 0; ni < 4; ++ni) {
      const int col = bcol + wc + ni * 16 + l15;
      const float bv = bias[col];
#pragma unroll
      for (int r = 0; r < 4; ++r) {
        const int row = brow + wr + mi * 16 + lg * 4 + r;  // C/D layout rows
        const float v = acc[mi][ni][r] + bv;
        if (EPI == 1) {
          Cf[(size_t)row * N + col] = v;
        } else {
          const int t = row >> 3, n = row & 7;  // row = t*NB + n
          const unsigned short hv = f2bf(v);
          if (col < DMODEL) {  // Q -> [n,h,t,dk]
            const int h = col >> 6, dk = col & 63;
            qb[(size_t)(n * NHEADS + h) * (T_SEQ * DK) + t * DK + dk] = hv;
          } else if (col < 2 * DMODEL) {  // K -> [n,h,t,dk]
            const int c2 = col - DMODEL;
            const int h = c2 >> 6, dk = c2 & 63;
            kb[(size_t)(n * NHEADS + h) * (T_SEQ * DK) + t * DK + dk] = hv;
          } else {  // V -> transposed [n,h,dk,t]
            const int c2 = col - 2 * DMODEL;
            const int h = c2 >> 6, dk = c2 & 63;
            vtb[(size_t)(n * NHEADS + h) * (T_SEQ * DK) + (size_t)dk * T_SEQ + t] = hv;
          }
        }
      }
    }
  }
}

// ---------------- fused causal attention, online softmax ------------------
// grid: (N*H)*8 blocks; block = 4 waves; wave w owns 16 q-rows of each of TWO
// paired q-tiles (j and 15-j) -> every block does exactly 17 K-tiles of work
// (modulo padding trim). No per-tile __syncthreads: P slab is wave-private,
// within-wave DS ordering is compiler-enforced.
#define PLD 72  // 144B row stride: breaks the stride-128B bank pattern

__global__ __launch_bounds__(256) void attn_kernel(
    const unsigned short* __restrict__ qb, const unsigned short* __restrict__ kb,
    const unsigned short* __restrict__ vtb, const int* __restrict__ lens,
    unsigned short* __restrict__ attn_out) {
  __shared__ unsigned short p_lds[4 * 16 * PLD];
  const int bid = blockIdx.x;
  const int nh = bid >> 3;        // (n*H + h)
  const int pr = bid & 7;         // pair index
  const int n = nh >> 4;
  const int h = nh & 15;
  const int w = threadIdx.x >> 6, lane = threadIdx.x & 63;
  const int l15 = lane & 15, lg = lane >> 4;
  const int len_n = lens[n];
  const int ltiles = (len_n + 63) >> 6;  // padding bound

  const unsigned short* kp_base = kb + (size_t)nh * (T_SEQ * DK);
  const unsigned short* vp_base = vtb + (size_t)nh * (T_SEQ * DK);
  const unsigned short* q_base = qb + (size_t)nh * (T_SEQ * DK);
  unsigned short* pw = p_lds + w * 16 * PLD;

#pragma unroll
  for (int p = 0; p < 2; ++p) {
    const int qt = p == 0 ? pr : 15 - pr;  // q-tile index
    const int q0 = qt * 64;

    // Q fragments (A-operand layout: row = l15, k = kk*32 + lg*8)
    const unsigned short* qp = q_base + (size_t)(q0 + w * 16 + l15) * DK;
    const bf16x8 qa0 = *reinterpret_cast<const bf16x8*>(qp + lg * 8);
    const bf16x8 qa1 = *reinterpret_cast<const bf16x8*>(qp + 32 + lg * 8);

    f32x4 o_acc[4] = {};
    float m_r[4], l_r[4];
#pragma unroll
    for (int r = 0; r < 4; ++r) { m_r[r] = -1e30f; l_r[r] = 0.f; }

    const int t_base = q0 + w * 16 + lg * 4;  // C/D layout row base
    int ntiles = qt + 1;                      // causal bound
    if (ltiles < ntiles) ntiles = ltiles;

    for (int tile = 0; tile < ntiles; ++tile) {
      const int s0 = tile * 64;
      f32x4 s_acc[4] = {};
#pragma unroll
      for (int ct = 0; ct < 4; ++ct) {  // S = Q K^T  (B-operand = K rows)
        const unsigned short* kp = kp_base + (size_t)(s0 + ct * 16 + l15) * DK + lg * 8;
        const bf16x8 kb0 = *reinterpret_cast<const bf16x8*>(kp);
        const bf16x8 kb1 = *reinterpret_cast<const bf16x8*>(kp + 32);
        s_acc[ct] = MFMA16(qa0, kb0, s_acc[ct]);
        s_acc[ct] = MFMA16(qa1, kb1, s_acc[ct]);
      }
      // scale + causal/padding mask
      float sv[4][4];
#pragma unroll
      for (int ct = 0; ct < 4; ++ct) {
        const int s = s0 + ct * 16 + l15;
#pragma unroll
        for (int r = 0; r < 4; ++r) {
          const int t = t_base + r;
          const float v = s_acc[ct][r] * 0.125f;  // 1/sqrt(64)
          sv[ct][r] = (s > t || s >= len_n) ? -1e30f : v;
        }
      }
      // online softmax per row r (row-reduce across the 16-lane group)
#pragma unroll
      for (int r = 0; r < 4; ++r) {
        float mx = fmaxf(fmaxf(sv[0][r], sv[1][r]), fmaxf(sv[2][r], sv[3][r]));
        mx = fmaxf(mx, __shfl_xor(mx, 1));
        mx = fmaxf(mx, __shfl_xor(mx, 2));
        mx = fmaxf(mx, __shfl_xor(mx, 4));
        mx = fmaxf(mx, __shfl_xor(mx, 8));
        const float mnew = fmaxf(m_r[r], mx);
        const float sc = __expf(m_r[r] - mnew);
        m_r[r] = mnew;
        float rs = 0.f;
#pragma unroll
        for (int ct = 0; ct < 4; ++ct) {
          const float pp = __expf(sv[ct][r] - mnew);
          sv[ct][r] = pp;
          rs += pp;
        }
        rs += __shfl_xor(rs, 1);
        rs += __shfl_xor(rs, 2);
        rs += __shfl_xor(rs, 4);
        rs += __shfl_xor(rs, 8);
        l_r[r] = l_r[r] * sc + rs;
#pragma unroll
        for (int ct = 0; ct < 4; ++ct) o_acc[ct][r] *= sc;
        // write P (bf16) into per-wave LDS slab, [row][s] layout
#pragma unroll
        for (int ct = 0; ct < 4; ++ct)
          pw[(lg * 4 + r) * PLD + ct * 16 + l15] = f2bf(sv[ct][r]);
      }
      // PV: A-operand from LDS P, B-operand = contiguous rows of V^T
      // (no barrier: slab is wave-private; DS ops in-order within wave)
      const bf16x8 pa0 = *reinterpret_cast<const bf16x8*>(pw + l15 * PLD + lg * 8);
      const bf16x8 pa1 = *reinterpret_cast<const bf16x8*>(pw + l15 * PLD + 32 + lg * 8);
#pragma unroll
      for (int ct = 0; ct < 4; ++ct) {
        const unsigned short* vp = vp_base + (size_t)(ct * 16 + l15) * T_SEQ + s0 + lg * 8;
        const bf16x8 vb0 = *reinterpret_cast<const bf16x8*>(vp);
        const bf16x8 vb1 = *reinterpret_cast<const bf16x8*>(vp + 32);
        o_acc[ct] = MFMA16(pa0, vb0, o_acc[ct]);
        o_acc[ct] = MFMA16(pa1, vb1, o_acc[ct]);
      }
    }

    // epilogue: normalize by l and store attn output bf16 [t, n, d]
    float inv_l[4];
#pragma unroll
    for (int r = 0; r < 4; ++r) inv_l[r] = 1.0f / l_r[r];
#pragma unroll
    for (int ct = 0; ct < 4; ++ct) {
      const int d = h * DK + ct * 16 + l15;
#pragma unroll
      for (int r = 0; r < 4; ++r) {
        const int t = t_base + r;
        attn_out[((size_t)t * NB + n) * DMODEL + d] = f2bf(o_acc[ct][r] * inv_l[r]);
      }
    }
  }
}

// ---------------------------------------------------------------------------
extern "C" void kernel_launch(void* const* d_in, const int* in_sizes, int n_in,
                              void* d_out, int out_size, void* d_ws, size_t ws_size,
                              hipStream_t stream) {
  const float* x = (const float*)d_in[0];
  const float* w_in = (const float*)d_in[1];
  const float* b_in = (const float*)d_in[2];
  const float* w_o = (const float*)d_in[3];
  const float* b_o = (const float*)d_in[4];
  // d_in[5] attn_mask: causal triu(k=1) -- computed analytically in-kernel
  const void* kpm = (const void*)d_in[6];
  float* out = (float*)d_out;

  char* ws = (char*)d_ws;
  // workspace layout (bytes)
  unsigned short* x_bf = (unsigned short*)(ws + 0);           // 16.78 MB
  unsigned short* win_bf = (unsigned short*)(ws + 16777216);  // 6.29 MB
  unsigned short* wo_bf = (unsigned short*)(ws + 23068672);   // 2.10 MB
  unsigned short* qb = (unsigned short*)(ws + 25165824);      // 16.78 MB
  unsigned short* kb = (unsigned short*)(ws + 41943040);      // 16.78 MB
  unsigned short* vtb = (unsigned short*)(ws + 58720256);     // 16.78 MB
  unsigned short* attn_bf = (unsigned short*)(ws + 75497472); // 16.78 MB
  int* lens = (int*)(ws + 92274688);                          // 32 B

  // conversions
  cvt_f32_bf16<<<(T_SEQ * NB * DMODEL / 4 + 255) / 256, 256, 0, stream>>>(x, x_bf,
                                                                          T_SEQ * NB * DMODEL / 4);
  cvt_f32_bf16<<<(3 * DMODEL * DMODEL / 4 + 255) / 256, 256, 0, stream>>>(
      w_in, win_bf, 3 * DMODEL * DMODEL / 4);
  cvt_f32_bf16<<<(DMODEL * DMODEL / 4 + 255) / 256, 256, 0, stream>>>(w_o, wo_bf,
                                                                      DMODEL * DMODEL / 4);
  len_kernel<<<1, 64, 0, stream>>>(kpm, lens);

  // QKV projection: [8192,1024] x [3072,1024]^T, scatter epilogue
  gemm_bt_kernel<0><<<dim3(64, 24), 256, 0, stream>>>(x_bf, win_bf, b_in, nullptr, qb, kb, vtb,
                                                      T_SEQ * NB, 3 * DMODEL, DMODEL);
  // fused attention (paired q-tiles -> 1024 equal-work blocks)
  attn_kernel<<<NB * NHEADS * 8, 256, 0, stream>>>(qb, kb, vtb, lens, attn_bf);
  // output projection: [8192,1024] x [1024,1024]^T -> f32 out
  gemm_bt_kernel<1><<<dim3(64, 8), 256, 0, stream>>>(attn_bf, wo_bf, b_o, out, nullptr, nullptr,
                                                     nullptr, T_SEQ * NB, DMODEL, DMODEL);
}

// Round 5
// 336.759 us; speedup vs baseline: 1.1869x; 1.0289x over previous
//
#include <hip/hip_runtime.h>

// ---------------------------------------------------------------------------
// MultiAttention: x[T=1024,N=8,D=1024] -> QKV proj -> 16-head causal attention
// with key padding -> out proj. bf16 MFMA compute, f32 accumulation.
// Round 5: attention XCD-L2 locality swizzle + V-load hoist + interior-tile
// mask skip + rowsum-via-MFMA(ones).
// ---------------------------------------------------------------------------

#define T_SEQ 1024
#define NB 8
#define DMODEL 1024
#define NHEADS 16
#define DK 64

typedef __attribute__((ext_vector_type(8))) short bf16x8;
typedef __attribute__((ext_vector_type(4))) float f32x4;

#define MFMA16(a, b, c) __builtin_amdgcn_mfma_f32_16x16x32_bf16((a), (b), (c), 0, 0, 0)

__device__ __forceinline__ unsigned short f2bf(float f) {
  unsigned int u = __float_as_uint(f);
  unsigned int r = (u + 0x7FFFu + ((u >> 16) & 1u)) >> 16;  // RNE
  return (unsigned short)r;
}

__device__ __forceinline__ void gload16(const void* g, void* l) {
  __builtin_amdgcn_global_load_lds((const __attribute__((address_space(1))) void*)g,
                                   (__attribute__((address_space(3))) void*)l, 16, 0, 0);
}

// ---------------- f32 -> bf16 conversion (vectorized) ----------------------
__global__ __launch_bounds__(256) void cvt_f32_bf16(const float* __restrict__ in,
                                                    unsigned short* __restrict__ out,
                                                    int n4) {
  int i = blockIdx.x * blockDim.x + threadIdx.x;
  if (i >= n4) return;
  float4 v = reinterpret_cast<const float4*>(in)[i];
  uint2 o;
  o.x = (unsigned)f2bf(v.x) | ((unsigned)f2bf(v.y) << 16);
  o.y = (unsigned)f2bf(v.z) | ((unsigned)f2bf(v.w) << 16);
  reinterpret_cast<uint2*>(out)[i] = o;
}

// ---------------- per-batch valid length from key_padding_mask -------------
// Detect element width (int32 vs byte bool) from the first 8192 bytes.
__global__ void len_kernel(const void* __restrict__ kpm_raw, int* __restrict__ lens) {
  const int* ki = (const int*)kpm_raw;
  const unsigned char* kb = (const unsigned char*)kpm_raw;
  const int lane = threadIdx.x;  // 1 block, 64 threads
  int bad = 0;
  for (int i = lane; i < 2048; i += 64) {
    unsigned v = (unsigned)ki[i];
    bad |= (v != 0u && v != 1u && v != 0x3F800000u) ? 1 : 0;
  }
  bad = __any(bad);  // 1 -> byte elements, 0 -> 4-byte elements
  for (int n = 0; n < NB; ++n) {
    int cnt = 0;
    if (bad) {
      for (int s = lane; s < T_SEQ; s += 64) cnt += (kb[n * T_SEQ + s] == 0) ? 1 : 0;
    } else {
      for (int s = lane; s < T_SEQ; s += 64) cnt += (ki[n * T_SEQ + s] == 0) ? 1 : 0;
    }
    for (int m = 1; m < 64; m <<= 1) cnt += __shfl_xor(cnt, m);
    if (lane == 0) lens[n] = cnt;
  }
}

// ---------------- 128x128 bf16 GEMM, C = A * B^T + bias --------------------
template <int EPI>
__global__ __launch_bounds__(256) void gemm_bt_kernel(
    const unsigned short* __restrict__ A, const unsigned short* __restrict__ B,
    const float* __restrict__ bias, float* __restrict__ Cf,
    unsigned short* __restrict__ qb, unsigned short* __restrict__ kb,
    unsigned short* __restrict__ vtb, int M, int N, int K) {
  __shared__ unsigned short lds_a[128 * 32];
  __shared__ unsigned short lds_b[128 * 32];
  const int tid = threadIdx.x;
  const int brow = blockIdx.x * 128;
  const int bcol = blockIdx.y * 128;
  const int w = tid >> 6, lane = tid & 63;
  const int l15 = lane & 15, lg = lane >> 4;
  const int wr = (w >> 1) * 64, wc = (w & 1) * 64;  // 2x2 wave grid, 64x64 each

  f32x4 acc[4][4] = {};

  for (int k0 = 0; k0 < K; k0 += 32) {
#pragma unroll
    for (int i = 0; i < 2; ++i) {
      int seg = i * 256 + tid;           // 512 segments of 16B per tile
      int row = seg >> 2;
      int qq = (seg & 3) * 8;
      gload16(A + (size_t)(brow + row) * K + k0 + qq, lds_a + seg * 8);
      gload16(B + (size_t)(bcol + row) * K + k0 + qq, lds_b + seg * 8);
    }
    __syncthreads();  // drains vmcnt -> staged data visible
    bf16x8 af[4], bfr[4];
#pragma unroll
    for (int mi = 0; mi < 4; ++mi)
      af[mi] = *reinterpret_cast<const bf16x8*>(lds_a + (wr + mi * 16 + l15) * 32 + lg * 8);
#pragma unroll
    for (int ni = 0; ni < 4; ++ni)
      bfr[ni] = *reinterpret_cast<const bf16x8*>(lds_b + (wc + ni * 16 + l15) * 32 + lg * 8);
#pragma unroll
    for (int mi = 0; mi < 4; ++mi)
#pragma unroll
      for (int ni = 0; ni < 4; ++ni)
        acc[mi][ni] = MFMA16(af[mi], bfr[ni], acc[mi][ni]);
    __syncthreads();  // all reads done before next stage overwrites
  }

#pragma unroll
  for (int mi = 0; mi < 4; ++mi) {
#pragma unroll
    for (int ni = 0; ni < 4; ++ni) {
      const int col = bcol + wc + ni * 16 + l15;
      const float bv = bias[col];
#pragma unroll
      for (int r = 0; r < 4; ++r) {
        const int row = brow + wr + mi * 16 + lg * 4 + r;  // C/D layout rows
        const float v = acc[mi][ni][r] + bv;
        if (EPI == 1) {
          Cf[(size_t)row * N + col] = v;
        } else {
          const int t = row >> 3, n = row & 7;  // row = t*NB + n
          const unsigned short hv = f2bf(v);
          if (col < DMODEL) {  // Q -> [n,h,t,dk]
            const int h = col >> 6, dk = col & 63;
            qb[(size_t)(n * NHEADS + h) * (T_SEQ * DK) + t * DK + dk] = hv;
          } else if (col < 2 * DMODEL) {  // K -> [n,h,t,dk]
            const int c2 = col - DMODEL;
            const int h = c2 >> 6, dk = c2 & 63;
            kb[(size_t)(n * NHEADS + h) * (T_SEQ * DK) + t * DK + dk] = hv;
          } else {  // V -> transposed [n,h,dk,t]
            const int c2 = col - 2 * DMODEL;
            const int h = c2 >> 6, dk = c2 & 63;
            vtb[(size_t)(n * NHEADS + h) * (T_SEQ * DK) + (size_t)dk * T_SEQ + t] = hv;
          }
        }
      }
    }
  }
}

// ---------------- fused causal attention, online softmax ------------------
// grid: 1024 blocks; block = 4 waves; wave w owns 16 q-rows of each of TWO
// paired q-tiles (j, 15-j) -> every block = 17 K-tiles (mod padding trim).
// XCD swizzle: xcd = bid&7; heads {x,x+8,...} + all 8 pair-blocks of a head
// stay on one XCD -> per-XCD K/V working set = 16 heads x 256KB = 4MB = L2.
#define PLD 72  // 144B row stride: breaks the stride-128B bank pattern

__global__ __launch_bounds__(256) void attn_kernel(
    const unsigned short* __restrict__ qb, const unsigned short* __restrict__ kb,
    const unsigned short* __restrict__ vtb, const int* __restrict__ lens,
    unsigned short* __restrict__ attn_out) {
  __shared__ unsigned short p_lds[4 * 16 * PLD];
  const int bid = blockIdx.x;
  const int x = bid & 7;           // hw XCD (round-robin dispatch)
  const int rem = bid >> 3;
  const int nh = (rem & 15) * 8 + x;  // (n*H + h): 16 heads per XCD
  const int pr = rem >> 4;            // pair index 0..7
  const int n = nh >> 4;
  const int h = nh & 15;
  const int w = threadIdx.x >> 6, lane = threadIdx.x & 63;
  const int l15 = lane & 15, lg = lane >> 4;
  const int len_n = lens[n];
  const int ltiles = (len_n + 63) >> 6;  // padding bound

  const unsigned short* kp_base = kb + (size_t)nh * (T_SEQ * DK);
  const unsigned short* vp_base = vtb + (size_t)nh * (T_SEQ * DK);
  const unsigned short* q_base = qb + (size_t)nh * (T_SEQ * DK);
  unsigned short* pw = p_lds + w * 16 * PLD;

  bf16x8 ones;
#pragma unroll
  for (int j = 0; j < 8; ++j) ones[j] = (short)0x3F80;  // bf16 1.0

#pragma unroll
  for (int p = 0; p < 2; ++p) {
    const int qt = p == 0 ? pr : 15 - pr;  // q-tile index
    const int q0 = qt * 64;

    // Q fragments (A-operand layout: row = l15, k = kk*32 + lg*8)
    const unsigned short* qp = q_base + (size_t)(q0 + w * 16 + l15) * DK;
    const bf16x8 qa0 = *reinterpret_cast<const bf16x8*>(qp + lg * 8);
    const bf16x8 qa1 = *reinterpret_cast<const bf16x8*>(qp + 32 + lg * 8);

    f32x4 o_acc[4] = {};
    float m_r[4], l_r[4];
#pragma unroll
    for (int r = 0; r < 4; ++r) { m_r[r] = -1e30f; l_r[r] = 0.f; }

    const int t_base = q0 + w * 16 + lg * 4;  // C/D layout row base
    int ntiles = qt + 1;                      // causal bound
    if (ltiles < ntiles) ntiles = ltiles;

    for (int tile = 0; tile < ntiles; ++tile) {
      const int s0 = tile * 64;
      f32x4 s_acc[4] = {};
#pragma unroll
      for (int ct = 0; ct < 4; ++ct) {  // S = Q K^T  (B-operand = K rows)
        const unsigned short* kp = kp_base + (size_t)(s0 + ct * 16 + l15) * DK + lg * 8;
        const bf16x8 kb0 = *reinterpret_cast<const bf16x8*>(kp);
        const bf16x8 kb1 = *reinterpret_cast<const bf16x8*>(kp + 32);
        s_acc[ct] = MFMA16(qa0, kb0, s_acc[ct]);
        s_acc[ct] = MFMA16(qa1, kb1, s_acc[ct]);
      }
      // hoist V loads: issue now so latency hides under softmax VALU
      bf16x8 vb[4][2];
#pragma unroll
      for (int ct = 0; ct < 4; ++ct) {
        const unsigned short* vp = vp_base + (size_t)(ct * 16 + l15) * T_SEQ + s0 + lg * 8;
        vb[ct][0] = *reinterpret_cast<const bf16x8*>(vp);
        vb[ct][1] = *reinterpret_cast<const bf16x8*>(vp + 32);
      }
      // scale + mask (only diagonal / len-boundary tiles pay the mask pass)
      float sv[4][4];
      const bool need_mask = (tile == qt) | (((tile + 1) << 6) > len_n);
      if (need_mask) {
#pragma unroll
        for (int ct = 0; ct < 4; ++ct) {
          const int s = s0 + ct * 16 + l15;
#pragma unroll
          for (int r = 0; r < 4; ++r) {
            const int t = t_base + r;
            const float v = s_acc[ct][r] * 0.125f;  // 1/sqrt(64)
            sv[ct][r] = (s > t || s >= len_n) ? -1e30f : v;
          }
        }
      } else {
#pragma unroll
        for (int ct = 0; ct < 4; ++ct)
#pragma unroll
          for (int r = 0; r < 4; ++r) sv[ct][r] = s_acc[ct][r] * 0.125f;
      }
      // online softmax per row r: max via shfl tree, sum via MFMA(ones)
      float sc_r[4];
#pragma unroll
      for (int r = 0; r < 4; ++r) {
        float mx = fmaxf(fmaxf(sv[0][r], sv[1][r]), fmaxf(sv[2][r], sv[3][r]));
        mx = fmaxf(mx, __shfl_xor(mx, 1));
        mx = fmaxf(mx, __shfl_xor(mx, 2));
        mx = fmaxf(mx, __shfl_xor(mx, 4));
        mx = fmaxf(mx, __shfl_xor(mx, 8));
        const float mnew = fmaxf(m_r[r], mx);
        sc_r[r] = __expf(m_r[r] - mnew);
        m_r[r] = mnew;
#pragma unroll
        for (int ct = 0; ct < 4; ++ct) {
          const float pp = __expf(sv[ct][r] - mnew);
          pw[(lg * 4 + r) * PLD + ct * 16 + l15] = f2bf(pp);
        }
#pragma unroll
        for (int ct = 0; ct < 4; ++ct) o_acc[ct][r] *= sc_r[r];
      }
      // PV: A-operand from LDS P, B-operand = hoisted V^T fragments
      // (no barrier: slab is wave-private; DS ops in-order within wave)
      const bf16x8 pa0 = *reinterpret_cast<const bf16x8*>(pw + l15 * PLD + lg * 8);
      const bf16x8 pa1 = *reinterpret_cast<const bf16x8*>(pw + l15 * PLD + 32 + lg * 8);
      f32x4 lacc = {};
      lacc = MFMA16(pa0, ones, lacc);  // row-sums of P -> lacc[r], rows match o_acc
      lacc = MFMA16(pa1, ones, lacc);
#pragma unroll
      for (int ct = 0; ct < 4; ++ct) {
        o_acc[ct] = MFMA16(pa0, vb[ct][0], o_acc[ct]);
        o_acc[ct] = MFMA16(pa1, vb[ct][1], o_acc[ct]);
      }
#pragma unroll
      for (int r = 0; r < 4; ++r) l_r[r] = l_r[r] * sc_r[r] + lacc[r];
    }

    // epilogue: normalize by l and store attn output bf16 [t, n, d]
    float inv_l[4];
#pragma unroll
    for (int r = 0; r < 4; ++r) inv_l[r] = 1.0f / l_r[r];
#pragma unroll
    for (int ct = 0; ct < 4; ++ct) {
      const int d = h * DK + ct * 16 + l15;
#pragma unroll
      for (int r = 0; r < 4; ++r) {
        const int t = t_base + r;
        attn_out[((size_t)t * NB + n) * DMODEL + d] = f2bf(o_acc[ct][r] * inv_l[r]);
      }
    }
  }
}

// ---------------------------------------------------------------------------
extern "C" void kernel_launch(void* const* d_in, const int* in_sizes, int n_in,
                              void* d_out, int out_size, void* d_ws, size_t ws_size,
                              hipStream_t stream) {
  const float* x = (const float*)d_in[0];
  const float* w_in = (const float*)d_in[1];
  const float* b_in = (const float*)d_in[2];
  const float* w_o = (const float*)d_in[3];
  const float* b_o = (const float*)d_in[4];
  // d_in[5] attn_mask: causal triu(k=1) -- computed analytically in-kernel
  const void* kpm = (const void*)d_in[6];
  float* out = (float*)d_out;

  char* ws = (char*)d_ws;
  // workspace layout (bytes)
  unsigned short* x_bf = (unsigned short*)(ws + 0);           // 16.78 MB
  unsigned short* win_bf = (unsigned short*)(ws + 16777216);  // 6.29 MB
  unsigned short* wo_bf = (unsigned short*)(ws + 23068672);   // 2.10 MB
  unsigned short* qb = (unsigned short*)(ws + 25165824);      // 16.78 MB
  unsigned short* kb = (unsigned short*)(ws + 41943040);      // 16.78 MB
  unsigned short* vtb = (unsigned short*)(ws + 58720256);     // 16.78 MB
  unsigned short* attn_bf = (unsigned short*)(ws + 75497472); // 16.78 MB
  int* lens = (int*)(ws + 92274688);                          // 32 B

  // conversions
  cvt_f32_bf16<<<(T_SEQ * NB * DMODEL / 4 + 255) / 256, 256, 0, stream>>>(x, x_bf,
                                                                          T_SEQ * NB * DMODEL / 4);
  cvt_f32_bf16<<<(3 * DMODEL * DMODEL / 4 + 255) / 256, 256, 0, stream>>>(
      w_in, win_bf, 3 * DMODEL * DMODEL / 4);
  cvt_f32_bf16<<<(DMODEL * DMODEL / 4 + 255) / 256, 256, 0, stream>>>(w_o, wo_bf,
                                                                      DMODEL * DMODEL / 4);
  len_kernel<<<1, 64, 0, stream>>>(kpm, lens);

  // QKV projection: [8192,1024] x [3072,1024]^T, scatter epilogue
  gemm_bt_kernel<0><<<dim3(64, 24), 256, 0, stream>>>(x_bf, win_bf, b_in, nullptr, qb, kb, vtb,
                                                      T_SEQ * NB, 3 * DMODEL, DMODEL);
  // fused attention (paired q-tiles, XCD-local heads)
  attn_kernel<<<NB * NHEADS * 8, 256, 0, stream>>>(qb, kb, vtb, lens, attn_bf);
  // output projection: [8192,1024] x [1024,1024]^T -> f32 out
  gemm_bt_kernel<1><<<dim3(64, 8), 256, 0, stream>>>(attn_bf, wo_bf, b_o, out, nullptr, nullptr,
                                                     nullptr, T_SEQ * NB, DMODEL, DMODEL);
}

// Round 6
// 246.288 us; speedup vs baseline: 1.6228x; 1.3673x over previous
//
#include <hip/hip_runtime.h>

// ---------------------------------------------------------------------------
// MultiAttention: x[T=1024,N=8,D=1024] -> QKV proj -> 16-head causal attention
// with key padding -> out proj. bf16 MFMA compute, f32 accumulation.
// Round 6: attention K/V double-buffered in LDS via global_load_lds with
// counted-vmcnt raw-barrier pipeline (T3/T4), XOR-swizzled LDS, VGPR budget
// raised to 128 (__launch_bounds__(256,4)) so V-frag hoist survives regalloc.
// ---------------------------------------------------------------------------

#define T_SEQ 1024
#define NB 8
#define DMODEL 1024
#define NHEADS 16
#define DK 64

typedef __attribute__((ext_vector_type(8))) short bf16x8;
typedef __attribute__((ext_vector_type(4))) float f32x4;

#define MFMA16(a, b, c) __builtin_amdgcn_mfma_f32_16x16x32_bf16((a), (b), (c), 0, 0, 0)

__device__ __forceinline__ unsigned short f2bf(float f) {
  unsigned int u = __float_as_uint(f);
  unsigned int r = (u + 0x7FFFu + ((u >> 16) & 1u)) >> 16;  // RNE
  return (unsigned short)r;
}

__device__ __forceinline__ void gload16(const void* g, void* l) {
  __builtin_amdgcn_global_load_lds((const __attribute__((address_space(1))) void*)g,
                                   (__attribute__((address_space(3))) void*)l, 16, 0, 0);
}

// ---------------- f32 -> bf16 conversion (vectorized) ----------------------
__global__ __launch_bounds__(256) void cvt_f32_bf16(const float* __restrict__ in,
                                                    unsigned short* __restrict__ out,
                                                    int n4) {
  int i = blockIdx.x * blockDim.x + threadIdx.x;
  if (i >= n4) return;
  float4 v = reinterpret_cast<const float4*>(in)[i];
  uint2 o;
  o.x = (unsigned)f2bf(v.x) | ((unsigned)f2bf(v.y) << 16);
  o.y = (unsigned)f2bf(v.z) | ((unsigned)f2bf(v.w) << 16);
  reinterpret_cast<uint2*>(out)[i] = o;
}

// ---------------- per-batch valid length from key_padding_mask -------------
// Detect element width (int32 vs byte bool) from the first 8192 bytes.
__global__ void len_kernel(const void* __restrict__ kpm_raw, int* __restrict__ lens) {
  const int* ki = (const int*)kpm_raw;
  const unsigned char* kb = (const unsigned char*)kpm_raw;
  const int lane = threadIdx.x;  // 1 block, 64 threads
  int bad = 0;
  for (int i = lane; i < 2048; i += 64) {
    unsigned v = (unsigned)ki[i];
    bad |= (v != 0u && v != 1u && v != 0x3F800000u) ? 1 : 0;
  }
  bad = __any(bad);  // 1 -> byte elements, 0 -> 4-byte elements
  for (int n = 0; n < NB; ++n) {
    int cnt = 0;
    if (bad) {
      for (int s = lane; s < T_SEQ; s += 64) cnt += (kb[n * T_SEQ + s] == 0) ? 1 : 0;
    } else {
      for (int s = lane; s < T_SEQ; s += 64) cnt += (ki[n * T_SEQ + s] == 0) ? 1 : 0;
    }
    for (int m = 1; m < 64; m <<= 1) cnt += __shfl_xor(cnt, m);
    if (lane == 0) lens[n] = cnt;
  }
}

// ---------------- 128x128 bf16 GEMM, C = A * B^T + bias --------------------
template <int EPI>
__global__ __launch_bounds__(256) void gemm_bt_kernel(
    const unsigned short* __restrict__ A, const unsigned short* __restrict__ B,
    const float* __restrict__ bias, float* __restrict__ Cf,
    unsigned short* __restrict__ qb, unsigned short* __restrict__ kb,
    unsigned short* __restrict__ vtb, int M, int N, int K) {
  __shared__ unsigned short lds_a[128 * 32];
  __shared__ unsigned short lds_b[128 * 32];
  const int tid = threadIdx.x;
  const int brow = blockIdx.x * 128;
  const int bcol = blockIdx.y * 128;
  const int w = tid >> 6, lane = tid & 63;
  const int l15 = lane & 15, lg = lane >> 4;
  const int wr = (w >> 1) * 64, wc = (w & 1) * 64;  // 2x2 wave grid, 64x64 each

  f32x4 acc[4][4] = {};

  for (int k0 = 0; k0 < K; k0 += 32) {
#pragma unroll
    for (int i = 0; i < 2; ++i) {
      int seg = i * 256 + tid;           // 512 segments of 16B per tile
      int row = seg >> 2;
      int qq = (seg & 3) * 8;
      gload16(A + (size_t)(brow + row) * K + k0 + qq, lds_a + seg * 8);
      gload16(B + (size_t)(bcol + row) * K + k0 + qq, lds_b + seg * 8);
    }
    __syncthreads();  // drains vmcnt -> staged data visible
    bf16x8 af[4], bfr[4];
#pragma unroll
    for (int mi = 0; mi < 4; ++mi)
      af[mi] = *reinterpret_cast<const bf16x8*>(lds_a + (wr + mi * 16 + l15) * 32 + lg * 8);
#pragma unroll
    for (int ni = 0; ni < 4; ++ni)
      bfr[ni] = *reinterpret_cast<const bf16x8*>(lds_b + (wc + ni * 16 + l15) * 32 + lg * 8);
#pragma unroll
    for (int mi = 0; mi < 4; ++mi)
#pragma unroll
      for (int ni = 0; ni < 4; ++ni)
        acc[mi][ni] = MFMA16(af[mi], bfr[ni], acc[mi][ni]);
    __syncthreads();  // all reads done before next stage overwrites
  }

#pragma unroll
  for (int mi = 0; mi < 4; ++mi) {
#pragma unroll
    for (int ni = 0; ni < 4; ++ni) {
      const int col = bcol + wc + ni * 16 + l15;
      const float bv = bias[col];
#pragma unroll
      for (int r = 0; r < 4; ++r) {
        const int row = brow + wr + mi * 16 + lg * 4 + r;  // C/D layout rows
        const float v = acc[mi][ni][r] + bv;
        if (EPI == 1) {
          Cf[(size_t)row * N + col] = v;
        } else {
          const int t = row >> 3, n = row & 7;  // row = t*NB + n
          const unsigned short hv = f2bf(v);
          if (col < DMODEL) {  // Q -> [n,h,t,dk]
            const int h = col >> 6, dk = col & 63;
            qb[(size_t)(n * NHEADS + h) * (T_SEQ * DK) + t * DK + dk] = hv;
          } else if (col < 2 * DMODEL) {  // K -> [n,h,t,dk]
            const int c2 = col - DMODEL;
            const int h = c2 >> 6, dk = c2 & 63;
            kb[(size_t)(n * NHEADS + h) * (T_SEQ * DK) + t * DK + dk] = hv;
          } else {  // V -> transposed [n,h,dk,t]
            const int c2 = col - 2 * DMODEL;
            const int h = c2 >> 6, dk = c2 & 63;
            vtb[(size_t)(n * NHEADS + h) * (T_SEQ * DK) + (size_t)dk * T_SEQ + t] = hv;
          }
        }
      }
    }
  }
}

// ---------------- fused causal attention, online softmax ------------------
// grid: 1024 blocks; block = 4 waves; wave w owns 16 q-rows of each of TWO
// paired q-tiles (j, 15-j) -> every block = 17 K-tiles (mod padding trim).
// XCD swizzle: xcd = bid&7 -> per-XCD K/V working set = 16 heads x 256KB = L2.
// K/V: LDS double-buffer via global_load_lds; counted vmcnt(4) + raw barrier
// (loads for tile t+1 stay in flight across tile t's compute).
// LDS XOR-swizzle (chunk ^= row&7 on 16B chunks): pre-swizzled GLOBAL source
// (gload_lds dest must be linear) + swizzled ds_read -> 2-way max conflicts.
#define PLD 72  // 144B row stride for the P slab

#define WAITVM(N) asm volatile("s_waitcnt vmcnt(" #N ")" ::: "memory")

__device__ __forceinline__ void stage_kv(const unsigned short* kp_base,
                                         const unsigned short* vp_base, int s0,
                                         unsigned short* kl, unsigned short* vl, int tid) {
#pragma unroll
  for (int i = 0; i < 2; ++i) {
    const int seg = i * 256 + tid;            // 512 chunks of 16B each
    const int r = seg >> 3, c8 = seg & 7;     // row, stored chunk slot
    const int xc = (c8 ^ (r & 7)) * 8;        // logical chunk for this slot
    gload16(kp_base + (((size_t)(s0 + r)) << 6) + xc, kl + seg * 8);
    gload16(vp_base + (size_t)r * T_SEQ + s0 + xc, vl + seg * 8);
  }
}

__global__ __launch_bounds__(256, 4) void attn_kernel(
    const unsigned short* __restrict__ qb, const unsigned short* __restrict__ kb,
    const unsigned short* __restrict__ vtb, const int* __restrict__ lens,
    unsigned short* __restrict__ attn_out) {
  __shared__ unsigned short k_lds[2][64 * 64];  // 8KB x2
  __shared__ unsigned short v_lds[2][64 * 64];  // 8KB x2
  __shared__ unsigned short p_lds[4 * 16 * PLD];
  const int bid = blockIdx.x;
  const int x = bid & 7;              // hw XCD (round-robin dispatch)
  const int rem = bid >> 3;
  const int nh = (rem & 15) * 8 + x;  // (n*H + h): 16 heads per XCD
  const int pr = rem >> 4;            // pair index 0..7
  const int n = nh >> 4;
  const int h = nh & 15;
  const int tid = threadIdx.x;
  const int w = tid >> 6, lane = tid & 63;
  const int l15 = lane & 15, lg = lane >> 4;
  const int len_n = lens[n];
  const int ltiles = (len_n + 63) >> 6;  // padding bound

  const unsigned short* kp_base = kb + (size_t)nh * (T_SEQ * DK);
  const unsigned short* vp_base = vtb + (size_t)nh * (T_SEQ * DK);
  const unsigned short* q_base = qb + (size_t)nh * (T_SEQ * DK);
  unsigned short* pw = p_lds + w * 16 * PLD;

  bf16x8 ones;
#pragma unroll
  for (int j = 0; j < 8; ++j) ones[j] = (short)0x3F80;  // bf16 1.0

  int cur = 0;
#pragma unroll
  for (int p = 0; p < 2; ++p) {
    const int qt = p == 0 ? pr : 15 - pr;  // q-tile index
    const int q0 = qt * 64;

    // Q fragments (A-operand layout: row = l15, k = kk*32 + lg*8)
    const unsigned short* qp = q_base + (size_t)(q0 + w * 16 + l15) * DK;
    const bf16x8 qa0 = *reinterpret_cast<const bf16x8*>(qp + lg * 8);
    const bf16x8 qa1 = *reinterpret_cast<const bf16x8*>(qp + 32 + lg * 8);

    f32x4 o_acc[4] = {};
    float m_r[4], l_r[4];
#pragma unroll
    for (int r = 0; r < 4; ++r) { m_r[r] = -1e30f; l_r[r] = 0.f; }

    const int t_base = q0 + w * 16 + lg * 4;  // C/D layout row base
    int ntiles = qt + 1;                      // causal bound (block-uniform)
    if (ltiles < ntiles) ntiles = ltiles;

    // prologue: stage tile 0 into buf[cur]
    stage_kv(kp_base, vp_base, 0, k_lds[cur], v_lds[cur], tid);

    for (int tile = 0; tile < ntiles; ++tile) {
      const int s0 = tile * 64;
      // issue next tile's stage; wait only for CURRENT tile's 4 loads
      if (tile + 1 < ntiles) {
        stage_kv(kp_base, vp_base, s0 + 64, k_lds[cur ^ 1], v_lds[cur ^ 1], tid);
        WAITVM(4);
      } else {
        WAITVM(0);
      }
      __builtin_amdgcn_s_barrier();  // buf[cur] visible to all waves

      // S = Q K^T from LDS (swizzled chunks)
      f32x4 s_acc[4] = {};
#pragma unroll
      for (int ct = 0; ct < 4; ++ct) {
        const int rl = ct * 16 + l15;
        const int c0 = lg ^ (rl & 7);
        const bf16x8 kf0 = *reinterpret_cast<const bf16x8*>(&k_lds[cur][rl * 64 + c0 * 8]);
        const bf16x8 kf1 = *reinterpret_cast<const bf16x8*>(&k_lds[cur][rl * 64 + (c0 ^ 4) * 8]);
        s_acc[ct] = MFMA16(qa0, kf0, s_acc[ct]);
        s_acc[ct] = MFMA16(qa1, kf1, s_acc[ct]);
      }
      // hoist V fragment reads (LDS latency hides under softmax VALU)
      bf16x8 vb[4][2];
#pragma unroll
      for (int ct = 0; ct < 4; ++ct) {
        const int rl = ct * 16 + l15;
        const int c0 = lg ^ (rl & 7);
        vb[ct][0] = *reinterpret_cast<const bf16x8*>(&v_lds[cur][rl * 64 + c0 * 8]);
        vb[ct][1] = *reinterpret_cast<const bf16x8*>(&v_lds[cur][rl * 64 + (c0 ^ 4) * 8]);
      }
      // scale + mask (only diagonal / len-boundary tiles pay the mask pass)
      float sv[4][4];
      const bool need_mask = (tile == qt) | (((tile + 1) << 6) > len_n);
      if (need_mask) {
#pragma unroll
        for (int ct = 0; ct < 4; ++ct) {
          const int s = s0 + ct * 16 + l15;
#pragma unroll
          for (int r = 0; r < 4; ++r) {
            const int t = t_base + r;
            const float v = s_acc[ct][r] * 0.125f;  // 1/sqrt(64)
            sv[ct][r] = (s > t || s >= len_n) ? -1e30f : v;
          }
        }
      } else {
#pragma unroll
        for (int ct = 0; ct < 4; ++ct)
#pragma unroll
          for (int r = 0; r < 4; ++r) sv[ct][r] = s_acc[ct][r] * 0.125f;
      }
      // online softmax per row r: max via shfl tree, sum via MFMA(ones)
      float sc_r[4];
#pragma unroll
      for (int r = 0; r < 4; ++r) {
        float mx = fmaxf(fmaxf(sv[0][r], sv[1][r]), fmaxf(sv[2][r], sv[3][r]));
        mx = fmaxf(mx, __shfl_xor(mx, 1));
        mx = fmaxf(mx, __shfl_xor(mx, 2));
        mx = fmaxf(mx, __shfl_xor(mx, 4));
        mx = fmaxf(mx, __shfl_xor(mx, 8));
        const float mnew = fmaxf(m_r[r], mx);
        sc_r[r] = __expf(m_r[r] - mnew);
        m_r[r] = mnew;
#pragma unroll
        for (int ct = 0; ct < 4; ++ct) {
          const float pp = __expf(sv[ct][r] - mnew);
          pw[(lg * 4 + r) * PLD + ct * 16 + l15] = f2bf(pp);
        }
#pragma unroll
        for (int ct = 0; ct < 4; ++ct) o_acc[ct][r] *= sc_r[r];
      }
      // PV: A-operand from LDS P (wave-private slab, in-wave DS ordering)
      const bf16x8 pa0 = *reinterpret_cast<const bf16x8*>(pw + l15 * PLD + lg * 8);
      const bf16x8 pa1 = *reinterpret_cast<const bf16x8*>(pw + l15 * PLD + 32 + lg * 8);
      f32x4 lacc = {};
      lacc = MFMA16(pa0, ones, lacc);  // row-sums of P; rows match o_acc layout
      lacc = MFMA16(pa1, ones, lacc);
#pragma unroll
      for (int ct = 0; ct < 4; ++ct) {
        o_acc[ct] = MFMA16(pa0, vb[ct][0], o_acc[ct]);
        o_acc[ct] = MFMA16(pa1, vb[ct][1], o_acc[ct]);
      }
#pragma unroll
      for (int r = 0; r < 4; ++r) l_r[r] = l_r[r] * sc_r[r] + lacc[r];

      __builtin_amdgcn_s_barrier();  // all waves done reading buf[cur]
      cur ^= 1;
    }

    // epilogue: normalize by l and store attn output bf16 [t, n, d]
    float inv_l[4];
#pragma unroll
    for (int r = 0; r < 4; ++r) inv_l[r] = 1.0f / l_r[r];
#pragma unroll
    for (int ct = 0; ct < 4; ++ct) {
      const int d = h * DK + ct * 16 + l15;
#pragma unroll
      for (int r = 0; r < 4; ++r) {
        const int t = t_base + r;
        attn_out[((size_t)t * NB + n) * DMODEL + d] = f2bf(o_acc[ct][r] * inv_l[r]);
      }
    }
  }
}

// ---------------------------------------------------------------------------
extern "C" void kernel_launch(void* const* d_in, const int* in_sizes, int n_in,
                              void* d_out, int out_size, void* d_ws, size_t ws_size,
                              hipStream_t stream) {
  const float* x = (const float*)d_in[0];
  const float* w_in = (const float*)d_in[1];
  const float* b_in = (const float*)d_in[2];
  const float* w_o = (const float*)d_in[3];
  const float* b_o = (const float*)d_in[4];
  // d_in[5] attn_mask: causal triu(k=1) -- computed analytically in-kernel
  const void* kpm = (const void*)d_in[6];
  float* out = (float*)d_out;

  char* ws = (char*)d_ws;
  // workspace layout (bytes)
  unsigned short* x_bf = (unsigned short*)(ws + 0);           // 16.78 MB
  unsigned short* win_bf = (unsigned short*)(ws + 16777216);  // 6.29 MB
  unsigned short* wo_bf = (unsigned short*)(ws + 23068672);   // 2.10 MB
  unsigned short* qb = (unsigned short*)(ws + 25165824);      // 16.78 MB
  unsigned short* kb = (unsigned short*)(ws + 41943040);      // 16.78 MB
  unsigned short* vtb = (unsigned short*)(ws + 58720256);     // 16.78 MB
  unsigned short* attn_bf = (unsigned short*)(ws + 75497472); // 16.78 MB
  int* lens = (int*)(ws + 92274688);                          // 32 B

  // conversions
  cvt_f32_bf16<<<(T_SEQ * NB * DMODEL / 4 + 255) / 256, 256, 0, stream>>>(x, x_bf,
                                                                          T_SEQ * NB * DMODEL / 4);
  cvt_f32_bf16<<<(3 * DMODEL * DMODEL / 4 + 255) / 256, 256, 0, stream>>>(
      w_in, win_bf, 3 * DMODEL * DMODEL / 4);
  cvt_f32_bf16<<<(DMODEL * DMODEL / 4 + 255) / 256, 256, 0, stream>>>(w_o, wo_bf,
                                                                      DMODEL * DMODEL / 4);
  len_kernel<<<1, 64, 0, stream>>>(kpm, lens);

  // QKV projection: [8192,1024] x [3072,1024]^T, scatter epilogue
  gemm_bt_kernel<0><<<dim3(64, 24), 256, 0, stream>>>(x_bf, win_bf, b_in, nullptr, qb, kb, vtb,
                                                      T_SEQ * NB, 3 * DMODEL, DMODEL);
  // fused attention (paired q-tiles, XCD-local heads, LDS-pipelined K/V)
  attn_kernel<<<NB * NHEADS * 8, 256, 0, stream>>>(qb, kb, vtb, lens, attn_bf);
  // output projection: [8192,1024] x [1024,1024]^T -> f32 out
  gemm_bt_kernel<1><<<dim3(64, 8), 256, 0, stream>>>(attn_bf, wo_bf, b_o, out, nullptr, nullptr,
                                                     nullptr, T_SEQ * NB, DMODEL, DMODEL);
}

// Round 7
// 223.097 us; speedup vs baseline: 1.7915x; 1.1039x over previous
//
#include <hip/hip_runtime.h>

// ---------------------------------------------------------------------------
// MultiAttention: x[T=1024,N=8,D=1024] -> QKV proj -> 16-head causal attention
// with key padding -> out proj. bf16 MFMA compute, f32 accumulation.
// Round 7: GEMM1 writes V coalesced ([n,h,t,dk], same as K); separate LDS
// transpose kernel makes V^T for attention. Fused conversion kernel.
// ---------------------------------------------------------------------------

#define T_SEQ 1024
#define NB 8
#define DMODEL 1024
#define NHEADS 16
#define DK 64

typedef __attribute__((ext_vector_type(8))) short bf16x8;
typedef __attribute__((ext_vector_type(8))) unsigned short u16x8;
typedef __attribute__((ext_vector_type(4))) float f32x4;

#define MFMA16(a, b, c) __builtin_amdgcn_mfma_f32_16x16x32_bf16((a), (b), (c), 0, 0, 0)

__device__ __forceinline__ unsigned short f2bf(float f) {
  unsigned int u = __float_as_uint(f);
  unsigned int r = (u + 0x7FFFu + ((u >> 16) & 1u)) >> 16;  // RNE
  return (unsigned short)r;
}

__device__ __forceinline__ void gload16(const void* g, void* l) {
  __builtin_amdgcn_global_load_lds((const __attribute__((address_space(1))) void*)g,
                                   (__attribute__((address_space(3))) void*)l, 16, 0, 0);
}

// ---------------- fused f32 -> bf16 conversion (x, w_in, w_o) --------------
#define XQ (T_SEQ * NB * DMODEL / 4)
#define WIQ (3 * DMODEL * DMODEL / 4)
#define WOQ (DMODEL * DMODEL / 4)

__global__ __launch_bounds__(256) void cvt_all(const float* __restrict__ x,
                                               const float* __restrict__ w_in,
                                               const float* __restrict__ w_o,
                                               unsigned short* __restrict__ xb,
                                               unsigned short* __restrict__ wib,
                                               unsigned short* __restrict__ wob) {
  int i = blockIdx.x * blockDim.x + threadIdx.x;
  const float* src;
  unsigned short* dst;
  int j;
  if (i < XQ) {
    src = x; dst = xb; j = i;
  } else if (i < XQ + WIQ) {
    src = w_in; dst = wib; j = i - XQ;
  } else if (i < XQ + WIQ + WOQ) {
    src = w_o; dst = wob; j = i - XQ - WIQ;
  } else {
    return;
  }
  float4 v = reinterpret_cast<const float4*>(src)[j];
  uint2 o;
  o.x = (unsigned)f2bf(v.x) | ((unsigned)f2bf(v.y) << 16);
  o.y = (unsigned)f2bf(v.z) | ((unsigned)f2bf(v.w) << 16);
  reinterpret_cast<uint2*>(dst)[j] = o;
}

// ---------------- per-batch valid length from key_padding_mask -------------
// Detect element width (int32 vs byte bool) from the first 8192 bytes.
__global__ void len_kernel(const void* __restrict__ kpm_raw, int* __restrict__ lens) {
  const int* ki = (const int*)kpm_raw;
  const unsigned char* kb = (const unsigned char*)kpm_raw;
  const int lane = threadIdx.x;  // 1 block, 64 threads
  int bad = 0;
  for (int i = lane; i < 2048; i += 64) {
    unsigned v = (unsigned)ki[i];
    bad |= (v != 0u && v != 1u && v != 0x3F800000u) ? 1 : 0;
  }
  bad = __any(bad);  // 1 -> byte elements, 0 -> 4-byte elements
  for (int n = 0; n < NB; ++n) {
    int cnt = 0;
    if (bad) {
      for (int s = lane; s < T_SEQ; s += 64) cnt += (kb[n * T_SEQ + s] == 0) ? 1 : 0;
    } else {
      for (int s = lane; s < T_SEQ; s += 64) cnt += (ki[n * T_SEQ + s] == 0) ? 1 : 0;
    }
    for (int m = 1; m < 64; m <<= 1) cnt += __shfl_xor(cnt, m);
    if (lane == 0) lens[n] = cnt;
  }
}

// ---------------- 128x128 bf16 GEMM, C = A * B^T + bias --------------------
// EPI==0: scatter epilogue to q/k/v buffers, ALL in [n,h,t,dk] layout.
// EPI==1: f32 output C[row*N + col] (output projection).
template <int EPI>
__global__ __launch_bounds__(256) void gemm_bt_kernel(
    const unsigned short* __restrict__ A, const unsigned short* __restrict__ B,
    const float* __restrict__ bias, float* __restrict__ Cf,
    unsigned short* __restrict__ qb, unsigned short* __restrict__ kb,
    unsigned short* __restrict__ vb, int M, int N, int K) {
  __shared__ unsigned short lds_a[128 * 32];
  __shared__ unsigned short lds_b[128 * 32];
  const int tid = threadIdx.x;
  const int brow = blockIdx.x * 128;
  const int bcol = blockIdx.y * 128;
  const int w = tid >> 6, lane = tid & 63;
  const int l15 = lane & 15, lg = lane >> 4;
  const int wr = (w >> 1) * 64, wc = (w & 1) * 64;  // 2x2 wave grid, 64x64 each

  f32x4 acc[4][4] = {};

  for (int k0 = 0; k0 < K; k0 += 32) {
#pragma unroll
    for (int i = 0; i < 2; ++i) {
      int seg = i * 256 + tid;           // 512 segments of 16B per tile
      int row = seg >> 2;
      int qq = (seg & 3) * 8;
      gload16(A + (size_t)(brow + row) * K + k0 + qq, lds_a + seg * 8);
      gload16(B + (size_t)(bcol + row) * K + k0 + qq, lds_b + seg * 8);
    }
    __syncthreads();  // drains vmcnt -> staged data visible
    bf16x8 af[4], bfr[4];
#pragma unroll
    for (int mi = 0; mi < 4; ++mi)
      af[mi] = *reinterpret_cast<const bf16x8*>(lds_a + (wr + mi * 16 + l15) * 32 + lg * 8);
#pragma unroll
    for (int ni = 0; ni < 4; ++ni)
      bfr[ni] = *reinterpret_cast<const bf16x8*>(lds_b + (wc + ni * 16 + l15) * 32 + lg * 8);
#pragma unroll
    for (int mi = 0; mi < 4; ++mi)
#pragma unroll
      for (int ni = 0; ni < 4; ++ni)
        acc[mi][ni] = MFMA16(af[mi], bfr[ni], acc[mi][ni]);
    __syncthreads();  // all reads done before next stage overwrites
  }

#pragma unroll
  for (int mi = 0; mi < 4; ++mi) {
#pragma unroll
    for (int ni = 0; ni < 4; ++ni) {
      const int col = bcol + wc + ni * 16 + l15;
      const float bv = bias[col];
      unsigned short* basep = nullptr;
      if (EPI == 0) basep = col < DMODEL ? qb : (col < 2 * DMODEL ? kb : vb);
      const int c2 = col & (DMODEL - 1);
      const int hh = c2 >> 6, dk = c2 & 63;
#pragma unroll
      for (int r = 0; r < 4; ++r) {
        const int row = brow + wr + mi * 16 + lg * 4 + r;  // C/D layout rows
        const float v = acc[mi][ni][r] + bv;
        if (EPI == 1) {
          Cf[(size_t)row * N + col] = v;
        } else {
          const int t = row >> 3, n = row & 7;  // row = t*NB + n
          basep[(size_t)(n * NHEADS + hh) * (T_SEQ * DK) + t * DK + dk] = f2bf(v);
        }
      }
    }
  }
}

// ---------------- V transpose: [n,h,t,dk] -> [n,h,dk,t] --------------------
// grid: (N*H)*16 blocks (one 64x64 tile each); 256 threads.
__global__ __launch_bounds__(256) void v_transpose(const unsigned short* __restrict__ vin,
                                                   unsigned short* __restrict__ vout) {
  __shared__ unsigned short tl[64 * 72];  // +8 pad breaks bank patterns
  const int b = blockIdx.x;
  const int nh = b >> 4, tt = b & 15;
  const unsigned short* src = vin + (size_t)nh * (T_SEQ * DK) + (size_t)tt * 64 * DK;
  unsigned short* dst = vout + (size_t)nh * (T_SEQ * DK) + tt * 64;
  const int tid = threadIdx.x;
  // load 64 t-rows x 64 dk (coalesced 16B chunks) into padded LDS
#pragma unroll
  for (int i = 0; i < 2; ++i) {
    const int c = i * 256 + tid;         // 512 chunks
    const int t = c >> 3, d0 = (c & 7) * 8;
    *reinterpret_cast<u16x8*>(&tl[t * 72 + d0]) =
        *reinterpret_cast<const u16x8*>(src + t * DK + d0);
  }
  __syncthreads();
  // write 64 dk-rows x 64 t: lane gathers 8 t for fixed dk (2-way banks max)
#pragma unroll
  for (int i = 0; i < 2; ++i) {
    const int c = i * 256 + tid;
    const int dk = c & 63, t0 = (c >> 6) * 8;
    u16x8 o;
#pragma unroll
    for (int j = 0; j < 8; ++j) o[j] = tl[(t0 + j) * 72 + dk];
    *reinterpret_cast<u16x8*>(dst + (size_t)dk * T_SEQ + t0) = o;
  }
}

// ---------------- fused causal attention, online softmax ------------------
// grid: 1024 blocks; block = 4 waves; wave w owns 16 q-rows of each of TWO
// paired q-tiles (j, 15-j) -> every block = 17 K-tiles (mod padding trim).
// XCD swizzle: xcd = bid&7 -> per-XCD K/V working set = 16 heads x 256KB = L2.
// K/V: LDS double-buffer via global_load_lds; counted vmcnt(4) + raw barrier.
// LDS XOR-swizzle via pre-swizzled GLOBAL source + swizzled ds_read.
#define PLD 72  // 144B row stride for the P slab

#define WAITVM(N) asm volatile("s_waitcnt vmcnt(" #N ")" ::: "memory")

__device__ __forceinline__ void stage_kv(const unsigned short* kp_base,
                                         const unsigned short* vp_base, int s0,
                                         unsigned short* kl, unsigned short* vl, int tid) {
#pragma unroll
  for (int i = 0; i < 2; ++i) {
    const int seg = i * 256 + tid;            // 512 chunks of 16B each
    const int r = seg >> 3, c8 = seg & 7;     // row, stored chunk slot
    const int xc = (c8 ^ (r & 7)) * 8;        // logical chunk for this slot
    gload16(kp_base + (((size_t)(s0 + r)) << 6) + xc, kl + seg * 8);
    gload16(vp_base + (size_t)r * T_SEQ + s0 + xc, vl + seg * 8);
  }
}

__global__ __launch_bounds__(256, 4) void attn_kernel(
    const unsigned short* __restrict__ qb, const unsigned short* __restrict__ kb,
    const unsigned short* __restrict__ vtb, const int* __restrict__ lens,
    unsigned short* __restrict__ attn_out) {
  __shared__ unsigned short k_lds[2][64 * 64];  // 8KB x2
  __shared__ unsigned short v_lds[2][64 * 64];  // 8KB x2
  __shared__ unsigned short p_lds[4 * 16 * PLD];
  const int bid = blockIdx.x;
  const int x = bid & 7;              // hw XCD (round-robin dispatch)
  const int rem = bid >> 3;
  const int nh = (rem & 15) * 8 + x;  // (n*H + h): 16 heads per XCD
  const int pr = rem >> 4;            // pair index 0..7
  const int n = nh >> 4;
  const int h = nh & 15;
  const int tid = threadIdx.x;
  const int w = tid >> 6, lane = tid & 63;
  const int l15 = lane & 15, lg = lane >> 4;
  const int len_n = lens[n];
  const int ltiles = (len_n + 63) >> 6;  // padding bound

  const unsigned short* kp_base = kb + (size_t)nh * (T_SEQ * DK);
  const unsigned short* vp_base = vtb + (size_t)nh * (T_SEQ * DK);
  const unsigned short* q_base = qb + (size_t)nh * (T_SEQ * DK);
  unsigned short* pw = p_lds + w * 16 * PLD;

  bf16x8 ones;
#pragma unroll
  for (int j = 0; j < 8; ++j) ones[j] = (short)0x3F80;  // bf16 1.0

  int cur = 0;
#pragma unroll
  for (int p = 0; p < 2; ++p) {
    const int qt = p == 0 ? pr : 15 - pr;  // q-tile index
    const int q0 = qt * 64;

    // Q fragments (A-operand layout: row = l15, k = kk*32 + lg*8)
    const unsigned short* qp = q_base + (size_t)(q0 + w * 16 + l15) * DK;
    const bf16x8 qa0 = *reinterpret_cast<const bf16x8*>(qp + lg * 8);
    const bf16x8 qa1 = *reinterpret_cast<const bf16x8*>(qp + 32 + lg * 8);

    f32x4 o_acc[4] = {};
    float m_r[4], l_r[4];
#pragma unroll
    for (int r = 0; r < 4; ++r) { m_r[r] = -1e30f; l_r[r] = 0.f; }

    const int t_base = q0 + w * 16 + lg * 4;  // C/D layout row base
    int ntiles = qt + 1;                      // causal bound (block-uniform)
    if (ltiles < ntiles) ntiles = ltiles;

    // prologue: stage tile 0 into buf[cur]
    stage_kv(kp_base, vp_base, 0, k_lds[cur], v_lds[cur], tid);

    for (int tile = 0; tile < ntiles; ++tile) {
      const int s0 = tile * 64;
      // issue next tile's stage; wait only for CURRENT tile's 4 loads
      if (tile + 1 < ntiles) {
        stage_kv(kp_base, vp_base, s0 + 64, k_lds[cur ^ 1], v_lds[cur ^ 1], tid);
        WAITVM(4);
      } else {
        WAITVM(0);
      }
      __builtin_amdgcn_s_barrier();  // buf[cur] visible to all waves

      // S = Q K^T from LDS (swizzled chunks)
      f32x4 s_acc[4] = {};
#pragma unroll
      for (int ct = 0; ct < 4; ++ct) {
        const int rl = ct * 16 + l15;
        const int c0 = lg ^ (rl & 7);
        const bf16x8 kf0 = *reinterpret_cast<const bf16x8*>(&k_lds[cur][rl * 64 + c0 * 8]);
        const bf16x8 kf1 = *reinterpret_cast<const bf16x8*>(&k_lds[cur][rl * 64 + (c0 ^ 4) * 8]);
        s_acc[ct] = MFMA16(qa0, kf0, s_acc[ct]);
        s_acc[ct] = MFMA16(qa1, kf1, s_acc[ct]);
      }
      // hoist V fragment reads (LDS latency hides under softmax VALU)
      bf16x8 vb[4][2];
#pragma unroll
      for (int ct = 0; ct < 4; ++ct) {
        const int rl = ct * 16 + l15;
        const int c0 = lg ^ (rl & 7);
        vb[ct][0] = *reinterpret_cast<const bf16x8*>(&v_lds[cur][rl * 64 + c0 * 8]);
        vb[ct][1] = *reinterpret_cast<const bf16x8*>(&v_lds[cur][rl * 64 + (c0 ^ 4) * 8]);
      }
      // scale + mask (only diagonal / len-boundary tiles pay the mask pass)
      float sv[4][4];
      const bool need_mask = (tile == qt) | (((tile + 1) << 6) > len_n);
      if (need_mask) {
#pragma unroll
        for (int ct = 0; ct < 4; ++ct) {
          const int s = s0 + ct * 16 + l15;
#pragma unroll
          for (int r = 0; r < 4; ++r) {
            const int t = t_base + r;
            const float v = s_acc[ct][r] * 0.125f;  // 1/sqrt(64)
            sv[ct][r] = (s > t || s >= len_n) ? -1e30f : v;
          }
        }
      } else {
#pragma unroll
        for (int ct = 0; ct < 4; ++ct)
#pragma unroll
          for (int r = 0; r < 4; ++r) sv[ct][r] = s_acc[ct][r] * 0.125f;
      }
      // online softmax per row r: max via shfl tree, sum via MFMA(ones)
      float sc_r[4];
#pragma unroll
      for (int r = 0; r < 4; ++r) {
        float mx = fmaxf(fmaxf(sv[0][r], sv[1][r]), fmaxf(sv[2][r], sv[3][r]));
        mx = fmaxf(mx, __shfl_xor(mx, 1));
        mx = fmaxf(mx, __shfl_xor(mx, 2));
        mx = fmaxf(mx, __shfl_xor(mx, 4));
        mx = fmaxf(mx, __shfl_xor(mx, 8));
        const float mnew = fmaxf(m_r[r], mx);
        sc_r[r] = __expf(m_r[r] - mnew);
        m_r[r] = mnew;
#pragma unroll
        for (int ct = 0; ct < 4; ++ct) {
          const float pp = __expf(sv[ct][r] - mnew);
          pw[(lg * 4 + r) * PLD + ct * 16 + l15] = f2bf(pp);
        }
#pragma unroll
        for (int ct = 0; ct < 4; ++ct) o_acc[ct][r] *= sc_r[r];
      }
      // PV: A-operand from LDS P (wave-private slab, in-wave DS ordering)
      const bf16x8 pa0 = *reinterpret_cast<const bf16x8*>(pw + l15 * PLD + lg * 8);
      const bf16x8 pa1 = *reinterpret_cast<const bf16x8*>(pw + l15 * PLD + 32 + lg * 8);
      f32x4 lacc = {};
      lacc = MFMA16(pa0, ones, lacc);  // row-sums of P; rows match o_acc layout
      lacc = MFMA16(pa1, ones, lacc);
#pragma unroll
      for (int ct = 0; ct < 4; ++ct) {
        o_acc[ct] = MFMA16(pa0, vb[ct][0], o_acc[ct]);
        o_acc[ct] = MFMA16(pa1, vb[ct][1], o_acc[ct]);
      }
#pragma unroll
      for (int r = 0; r < 4; ++r) l_r[r] = l_r[r] * sc_r[r] + lacc[r];

      __builtin_amdgcn_s_barrier();  // all waves done reading buf[cur]
      cur ^= 1;
    }

    // epilogue: normalize by l and store attn output bf16 [t, n, d]
    float inv_l[4];
#pragma unroll
    for (int r = 0; r < 4; ++r) inv_l[r] = 1.0f / l_r[r];
#pragma unroll
    for (int ct = 0; ct < 4; ++ct) {
      const int d = h * DK + ct * 16 + l15;
#pragma unroll
      for (int r = 0; r < 4; ++r) {
        const int t = t_base + r;
        attn_out[((size_t)t * NB + n) * DMODEL + d] = f2bf(o_acc[ct][r] * inv_l[r]);
      }
    }
  }
}

// ---------------------------------------------------------------------------
extern "C" void kernel_launch(void* const* d_in, const int* in_sizes, int n_in,
                              void* d_out, int out_size, void* d_ws, size_t ws_size,
                              hipStream_t stream) {
  const float* x = (const float*)d_in[0];
  const float* w_in = (const float*)d_in[1];
  const float* b_in = (const float*)d_in[2];
  const float* w_o = (const float*)d_in[3];
  const float* b_o = (const float*)d_in[4];
  // d_in[5] attn_mask: causal triu(k=1) -- computed analytically in-kernel
  const void* kpm = (const void*)d_in[6];
  float* out = (float*)d_out;

  char* ws = (char*)d_ws;
  // workspace layout (bytes); attn_bf aliases x_bf (dead after GEMM1)
  unsigned short* x_bf = (unsigned short*)(ws + 0);           // 16.78 MB
  unsigned short* win_bf = (unsigned short*)(ws + 16777216);  // 6.29 MB
  unsigned short* wo_bf = (unsigned short*)(ws + 23068672);   // 2.10 MB
  unsigned short* qb = (unsigned short*)(ws + 25165824);      // 16.78 MB
  unsigned short* kb = (unsigned short*)(ws + 41943040);      // 16.78 MB
  unsigned short* vb = (unsigned short*)(ws + 58720256);      // 16.78 MB  [n,h,t,dk]
  unsigned short* vtb = (unsigned short*)(ws + 75497472);     // 16.78 MB  [n,h,dk,t]
  unsigned short* attn_bf = (unsigned short*)(ws + 0);        // alias x_bf
  int* lens = (int*)(ws + 92274688);                          // 32 B

  // fused conversions (x, w_in, w_o)
  cvt_all<<<(XQ + WIQ + WOQ + 255) / 256, 256, 0, stream>>>(x, w_in, w_o, x_bf, win_bf, wo_bf);
  len_kernel<<<1, 64, 0, stream>>>(kpm, lens);

  // QKV projection: [8192,1024] x [3072,1024]^T, coalesced scatter epilogue
  gemm_bt_kernel<0><<<dim3(64, 24), 256, 0, stream>>>(x_bf, win_bf, b_in, nullptr, qb, kb, vb,
                                                      T_SEQ * NB, 3 * DMODEL, DMODEL);
  // V transpose for attention PV operand
  v_transpose<<<NB * NHEADS * 16, 256, 0, stream>>>(vb, vtb);
  // fused attention (paired q-tiles, XCD-local heads, LDS-pipelined K/V)
  attn_kernel<<<NB * NHEADS * 8, 256, 0, stream>>>(qb, kb, vtb, lens, attn_bf);
  // output projection: [8192,1024] x [1024,1024]^T -> f32 out
  gemm_bt_kernel<1><<<dim3(64, 8), 256, 0, stream>>>(attn_bf, wo_bf, b_o, out, nullptr, nullptr,
                                                     nullptr, T_SEQ * NB, DMODEL, DMODEL);
}